// Round 7
// baseline (155.778 us; speedup 1.0000x reference)
//
#include <hip/hip_runtime.h>
#include <hip/hip_fp16.h>
#include <math.h>

#define N_NODES  100000
#define N_HID    128
#define N_ETYPES 10
#define N_EDGES  100000
#define TOT_EDGES (N_ETYPES * N_EDGES)   // 1,000,000

#define NSLICE    64        // dst slices: slice = dst*64/100000 (0.4 MB of rows each)
#define SLICE_CAP 16384     // fixed region per slice; mean 15625, sd ~124 -> 6 sigma safe
#define CPAD      16        // cursor stride: 64B per counter (device-scope atomic targets)
#define EPB_SC    2048      // edges per scatter block
#define NBLK_SC   ((TOT_EDGES + EPB_SC - 1) / EPB_SC)   // 489
#define NBLK_CV   ((N_NODES * N_HID) / (256 * 8))       // 6250 convert blocks
#define EPB_SCORE 128                                    // edges per score block
#define NBLK_SCORE (NSLICE * (SLICE_CAP / EPB_SCORE))   // 8192

#define EDGES_PER_HW 4      // fp32 fallback only

typedef __attribute__((ext_vector_type(2))) _Float16 h2v;
typedef __attribute__((ext_vector_type(4))) int i4v;   // native vec type: OK for nontemporal builtins

#if defined(__has_builtin)
#if __has_builtin(__builtin_amdgcn_fdot2)
#define HAVE_FDOT2 1
#endif
#endif

__device__ __forceinline__ float dot2acc(h2v a, h2v b, float c) {
#ifdef HAVE_FDOT2
    return __builtin_amdgcn_fdot2(a, b, c, false);
#else
    return c + (float)a.x * (float)b.x + (float)a.y * (float)b.y;
#endif
}

// VALU-only cross-lane reduce within 16-lane row groups (no DS pipe).
template<int CTRL>
__device__ __forceinline__ float ror_add(float p) {
    int r = __builtin_amdgcn_update_dpp(0, __float_as_int(p), CTRL, 0xF, 0xF, true);
    return p + __int_as_float(r);
}
__device__ __forceinline__ float row16_sum(float p) {
    p = ror_add<0x121>(p);  // row_ror:1
    p = ror_add<0x122>(p);  // row_ror:2
    p = ror_add<0x124>(p);  // row_ror:4
    p = ror_add<0x128>(p);  // row_ror:8
    return p;
}

__device__ __forceinline__ float dot_row(uint4 a, uint4 b, uint4 w) {
    union { uint4 u; h2v p[4]; } ua, ub, uw;
    ua.u = a; ub.u = b; uw.u = w;
    float p = dot2acc(ua.p[0], (h2v)(uw.p[0] * ub.p[0]), 0.0f);
    p = dot2acc(ua.p[1], (h2v)(uw.p[1] * ub.p[1]), p);
    p = dot2acc(ua.p[2], (h2v)(uw.p[2] * ub.p[2]), p);
    p = dot2acc(ua.p[3], (h2v)(uw.p[3] * ub.p[3]), p);
    return p;
}

// =================== phase bodies ===================

__device__ __forceinline__ void conv_vec8(const float* __restrict__ h,
                                          __half* __restrict__ h16, size_t off) {
    const float4 f0 = *(const float4*)(h + off);
    const float4 f1 = *(const float4*)(h + off + 4);
    union { uint4 u; __half2 p[4]; } pk;
    pk.p[0] = __floats2half2_rn(f0.x, f0.y);
    pk.p[1] = __floats2half2_rn(f0.z, f0.w);
    pk.p[2] = __floats2half2_rn(f1.x, f1.y);
    pk.p[3] = __floats2half2_rn(f1.z, f1.w);
    *(uint4*)(h16 + off) = pk.u;
}

__device__ __forceinline__ void wr16_rows(int tid,
    const float* __restrict__ W, const int* __restrict__ rel,
    __half* __restrict__ Wr16) {
    if (tid < (N_ETYPES * N_HID / 8)) {
        const int j = tid * 8;               // [0,1280)
        const int t = j >> 7;
        const int c = j & (N_HID - 1);
        const int r = rel[t];
        const float4 g0 = *(const float4*)(W + (size_t)r * N_HID + c);
        const float4 g1 = *(const float4*)(W + (size_t)r * N_HID + c + 4);
        union { uint4 u; __half2 p[4]; } pw;
        pw.p[0] = __floats2half2_rn(g0.x, g0.y);
        pw.p[1] = __floats2half2_rn(g0.z, g0.w);
        pw.p[2] = __floats2half2_rn(g1.x, g1.y);
        pw.p[3] = __floats2half2_rn(g1.z, g1.w);
        *(uint4*)(Wr16 + j) = pw.u;
    }
}

// record: lo = src(17) | dst[14:0]<<17 ; hi = dst>>15 (2) | ety<<2 (4) | off<<6 (17)
// cursor[] starts at 0 (memset); rec position = slice*SLICE_CAP + relative offset.
__device__ __forceinline__ void scatter_block(int vb, int tid,
    const int* __restrict__ src, const int* __restrict__ dst,
    int* __restrict__ cursor, uint2* __restrict__ rec,
    int* lcnt, int* lbase) {
    if (tid < NSLICE) lcnt[tid] = 0;
    __syncthreads();

    const int e0 = vb * EPB_SC + tid * 8;
    const bool active = (e0 < TOT_EDGES);   // TOT % 8 == 0 -> no straddle

    int ss[8], dd[8], sl[8];
    if (active) {
        const i4v s0 = __builtin_nontemporal_load((const i4v*)(src + e0));
        const i4v s1 = __builtin_nontemporal_load((const i4v*)(src + e0 + 4));
        const i4v d0 = __builtin_nontemporal_load((const i4v*)(dst + e0));
        const i4v d1 = __builtin_nontemporal_load((const i4v*)(dst + e0 + 4));
        ss[0]=s0.x; ss[1]=s0.y; ss[2]=s0.z; ss[3]=s0.w;
        ss[4]=s1.x; ss[5]=s1.y; ss[6]=s1.z; ss[7]=s1.w;
        dd[0]=d0.x; dd[1]=d0.y; dd[2]=d0.z; dd[3]=d0.w;
        dd[4]=d1.x; dd[5]=d1.y; dd[6]=d1.z; dd[7]=d1.w;
        #pragma unroll
        for (int k = 0; k < 8; ++k) {
            sl[k] = (int)(((unsigned long long)(unsigned)dd[k] * 1407374884ULL) >> 41);
            atomicAdd(&lcnt[sl[k]], 1);
        }
    }
    __syncthreads();
    if (tid < NSLICE) {
        const int c = lcnt[tid];
        lbase[tid] = c ? (tid * SLICE_CAP + atomicAdd(&cursor[tid * CPAD], c)) : 0;
        lcnt[tid] = 0;
    }
    __syncthreads();
    if (active) {
        #pragma unroll
        for (int k = 0; k < 8; ++k) {
            const int e   = e0 + k;
            const int ety = (int)(((unsigned long long)(unsigned)e * 1407374884ULL) >> 47);
            const int off = e - ety * N_EDGES;
            const int r   = atomicAdd(&lcnt[sl[k]], 1);
            const int pos = lbase[sl[k]] + r;
            const unsigned lo = (unsigned)ss[k] | ((unsigned)dd[k] << 17);
            const unsigned hi = ((unsigned)dd[k] >> 15) | ((unsigned)ety << 2) | ((unsigned)off << 6);
            rec[pos] = make_uint2(lo, hi);
        }
    }
}

// =================== dispatch 1: convert || scatter (independent streams) ===================
__global__ __launch_bounds__(256) void prep_kernel(
    const float* __restrict__ h, const float* __restrict__ W,
    const int*   __restrict__ rel,
    const int*   __restrict__ src, const int* __restrict__ dst,
    __half* __restrict__ h16, __half* __restrict__ Wr16,
    int* __restrict__ cursor, uint2* __restrict__ rec)
{
    __shared__ int lcnt[NSLICE];
    __shared__ int lbase[NSLICE];
    const int b   = blockIdx.x;
    const int tid = threadIdx.x;
    if (b < NBLK_SC) {
        scatter_block(b, tid, src, dst, cursor, rec, lcnt, lbase);
    } else {
        const int cb = b - NBLK_SC;
        conv_vec8(h, h16, ((size_t)cb * 256 + tid) * 8);
        if (cb == 0) wr16_rows(tid, W, rel, Wr16);
    }
}

// =================== dispatch 2: XCD/dst-slice phased score ===================
// Block b: x = b&7 (XCD), s = x + 8*((b>>3)>>7), chunk = (b>>3)&127.
// 128 edges/block as TWO 64-edge rounds fully software-pipelined: all 32 loads
// issued before any reduce. __launch_bounds__(256,3): VGPR cap ~168 so the
// compiler keeps them in flight (at the default cap of 32 VGPRs it serialized
// the loads into ~4-deep batches -> latency-bound at ~48us).
#define DECODE(r, sN, dN, tN, oN) \
    const unsigned sN = r.x & 131071u; \
    const unsigned dN = ((r.x >> 17) | (r.y << 15)) & 131071u; \
    const unsigned tN = (r.y >> 2) & 15u; \
    const unsigned oN = r.y >> 6;

__global__ __launch_bounds__(256, 3) void score_kernel(
    const __half* __restrict__ h16,
    const __half* __restrict__ Wr16,
    const uint2*  __restrict__ rec,
    const int*    __restrict__ cursor,
    float*        __restrict__ out)
{
    const int tid  = threadIdx.x;
    const int lane = tid & 63;
    const int g    = lane >> 4;
    const int gl   = lane & 15;
    const int wid  = tid >> 6;

    const int b     = blockIdx.x;
    const int x     = b & 7;
    const int j     = b >> 3;
    const int s     = x + ((j >> 7) << 3);
    const int chunk = j & 127;
    const int sbase = s << 14;                 // * SLICE_CAP
    const int cnt   = cursor[s * CPAD];        // edges in this slice
    const unsigned col = (unsigned)gl << 3;    // 8 halfs (16B) per lane

    const int eA = (chunk << 7) + (wid << 4);  // round A base for this wave
    const int eB = eA + 64;                    // round B base
    if (eA >= cnt) return;                     // uniform per wave

    // ---- issue all 8 rec loads ----
    const int iA0 = eA + g,      iA1 = eA + 4 + g,  iA2 = eA + 8 + g,  iA3 = eA + 12 + g;
    const int iB0 = eB + g,      iB1 = eB + 4 + g,  iB2 = eB + 8 + g,  iB3 = eB + 12 + g;
    const uint2 rA0 = rec[sbase + (iA0 < cnt ? iA0 : 0)];
    const uint2 rA1 = rec[sbase + (iA1 < cnt ? iA1 : 0)];
    const uint2 rA2 = rec[sbase + (iA2 < cnt ? iA2 : 0)];
    const uint2 rA3 = rec[sbase + (iA3 < cnt ? iA3 : 0)];
    const uint2 rB0 = rec[sbase + (iB0 < cnt ? iB0 : 0)];
    const uint2 rB1 = rec[sbase + (iB1 < cnt ? iB1 : 0)];
    const uint2 rB2 = rec[sbase + (iB2 < cnt ? iB2 : 0)];
    const uint2 rB3 = rec[sbase + (iB3 < cnt ? iB3 : 0)];

    DECODE(rA0, sA0, dA0, tA0, oA0)  DECODE(rA1, sA1, dA1, tA1, oA1)
    DECODE(rA2, sA2, dA2, tA2, oA2)  DECODE(rA3, sA3, dA3, tA3, oA3)
    DECODE(rB0, sB0, dB0, tB0, oB0)  DECODE(rB1, sB1, dB1, tB1, oB1)
    DECODE(rB2, sB2, dB2, tB2, oB2)  DECODE(rB3, sB3, dB3, tB3, oB3)

    // ---- issue all 24 row/W loads (src rows first: they are the L2-miss side) ----
    const uint4 A0 = *(const uint4*)(h16 + ((sA0 << 7) + col));
    const uint4 A1 = *(const uint4*)(h16 + ((sA1 << 7) + col));
    const uint4 A2 = *(const uint4*)(h16 + ((sA2 << 7) + col));
    const uint4 A3 = *(const uint4*)(h16 + ((sA3 << 7) + col));
    const uint4 A4 = *(const uint4*)(h16 + ((sB0 << 7) + col));
    const uint4 A5 = *(const uint4*)(h16 + ((sB1 << 7) + col));
    const uint4 A6 = *(const uint4*)(h16 + ((sB2 << 7) + col));
    const uint4 A7 = *(const uint4*)(h16 + ((sB3 << 7) + col));
    const uint4 B0 = *(const uint4*)(h16 + ((dA0 << 7) + col));
    const uint4 B1 = *(const uint4*)(h16 + ((dA1 << 7) + col));
    const uint4 B2 = *(const uint4*)(h16 + ((dA2 << 7) + col));
    const uint4 B3 = *(const uint4*)(h16 + ((dA3 << 7) + col));
    const uint4 B4 = *(const uint4*)(h16 + ((dB0 << 7) + col));
    const uint4 B5 = *(const uint4*)(h16 + ((dB1 << 7) + col));
    const uint4 B6 = *(const uint4*)(h16 + ((dB2 << 7) + col));
    const uint4 B7 = *(const uint4*)(h16 + ((dB3 << 7) + col));
    const uint4 W0 = *(const uint4*)(Wr16 + ((tA0 << 7) + col));
    const uint4 W1 = *(const uint4*)(Wr16 + ((tA1 << 7) + col));
    const uint4 W2 = *(const uint4*)(Wr16 + ((tA2 << 7) + col));
    const uint4 W3 = *(const uint4*)(Wr16 + ((tA3 << 7) + col));
    const uint4 W4 = *(const uint4*)(Wr16 + ((tB0 << 7) + col));
    const uint4 W5 = *(const uint4*)(Wr16 + ((tB1 << 7) + col));
    const uint4 W6 = *(const uint4*)(Wr16 + ((tB2 << 7) + col));
    const uint4 W7 = *(const uint4*)(Wr16 + ((tB3 << 7) + col));

    // ---- reduce (in issue order) ----
    const float pA0 = row16_sum(dot_row(A0, B0, W0));
    const float pA1 = row16_sum(dot_row(A1, B1, W1));
    const float pA2 = row16_sum(dot_row(A2, B2, W2));
    const float pA3 = row16_sum(dot_row(A3, B3, W3));
    const float pB0 = row16_sum(dot_row(A4, B4, W4));
    const float pB1 = row16_sum(dot_row(A5, B5, W5));
    const float pB2 = row16_sum(dot_row(A6, B6, W6));
    const float pB3 = row16_sum(dot_row(A7, B7, W7));

    if (gl < 4) {
        const int ii = eA + (gl << 2) + g;
        if (ii < cnt) {
            const float    res = (gl == 0) ? pA0 : (gl == 1) ? pA1 : (gl == 2) ? pA2 : pA3;
            const unsigned tt  = (gl == 0) ? tA0 : (gl == 1) ? tA1 : (gl == 2) ? tA2 : tA3;
            const unsigned oo  = (gl == 0) ? oA0 : (gl == 1) ? oA1 : (gl == 2) ? oA2 : oA3;
            __builtin_nontemporal_store(1.0f / (1.0f + __expf(-res)), out + tt * N_EDGES + oo);
        }
        const int jj = eB + (gl << 2) + g;
        if (jj < cnt) {
            const float    res = (gl == 0) ? pB0 : (gl == 1) ? pB1 : (gl == 2) ? pB2 : pB3;
            const unsigned tt  = (gl == 0) ? tB0 : (gl == 1) ? tB1 : (gl == 2) ? tB2 : tB3;
            const unsigned oo  = (gl == 0) ? oB0 : (gl == 1) ? oB1 : (gl == 2) ? oB2 : oB3;
            __builtin_nontemporal_store(1.0f / (1.0f + __expf(-res)), out + tt * N_EDGES + oo);
        }
    }
}

// ---------------- fp32 fallback (no workspace) ----------------
__global__ __launch_bounds__(256) void distmult_score_f32_kernel(
    const float* __restrict__ h,
    const float* __restrict__ W,
    const int*   __restrict__ src,
    const int*   __restrict__ dst,
    const int*   __restrict__ rel,
    float*       __restrict__ out)
{
    const int t    = blockIdx.y;
    const int lane = threadIdx.x & 31;
    const int hw   = (blockIdx.x << 3) + (threadIdx.x >> 5);
    const int r = rel[t];
    const float4 w4 = ((const float4*)(W + (size_t)r * N_HID))[lane];
    const long base = (long)t * N_EDGES;
    const int  e0   = hw * EDGES_PER_HW;
    float res = 0.0f;
    #pragma unroll
    for (int k = 0; k < EDGES_PER_HW; ++k) {
        const int e = e0 + k;
        const int s = src[base + e];
        const int d = dst[base + e];
        const float4 a = ((const float4*)(h + (size_t)s * N_HID))[lane];
        const float4 b = ((const float4*)(h + (size_t)d * N_HID))[lane];
        float p = a.x * w4.x * b.x + a.y * w4.y * b.y
                + a.z * w4.z * b.z + a.w * w4.w * b.w;
        p += __shfl_xor(p, 16, 64);
        p += __shfl_xor(p, 8, 64);
        p += __shfl_xor(p, 4, 64);
        p += __shfl_xor(p, 2, 64);
        p += __shfl_xor(p, 1, 64);
        if (lane == k) res = p;
    }
    if (lane < EDGES_PER_HW) {
        out[base + e0 + lane] = 1.0f / (1.0f + __expf(-res));
    }
}

extern "C" void kernel_launch(void* const* d_in, const int* in_sizes, int n_in,
                              void* d_out, int out_size, void* d_ws, size_t ws_size,
                              hipStream_t stream) {
    const float* h   = (const float*)d_in[0];
    const float* W   = (const float*)d_in[1];
    const int*   src = (const int*)d_in[2];
    const int*   dst = (const int*)d_in[3];
    const int*   rel = (const int*)d_in[4];
    float*       out = (float*)d_out;

    const size_t h16_bytes  = (size_t)N_NODES * N_HID * sizeof(__half);   // 25,600,000
    const size_t wr16_bytes = 4096;
    const size_t rec_bytes  = (size_t)NSLICE * SLICE_CAP * 8;             //  8,388,608
    const size_t cur_bytes  = (size_t)NSLICE * CPAD * sizeof(int);        //      4,096
    const size_t need_full  = h16_bytes + wr16_bytes + rec_bytes + cur_bytes;

    if (ws_size >= need_full) {
        char* w = (char*)d_ws;
        __half* h16    = (__half*)w;   w += h16_bytes;
        __half* Wr16   = (__half*)w;   w += wr16_bytes;
        uint2*  rec    = (uint2*)w;    w += rec_bytes;
        int*    cursor = (int*)w;

        (void)hipMemsetAsync(cursor, 0, cur_bytes, stream);
        prep_kernel<<<NBLK_SC + NBLK_CV, 256, 0, stream>>>(
            h, W, rel, src, dst, h16, Wr16, cursor, rec);
        score_kernel<<<NBLK_SCORE, 256, 0, stream>>>(h16, Wr16, rec, cursor, out);
    } else {
        dim3 grid(N_EDGES / (8 * EDGES_PER_HW), N_ETYPES);
        distmult_score_f32_kernel<<<grid, 256, 0, stream>>>(h, W, src, dst, rel, out);
    }
}